// Round 6
// baseline (353.032 us; speedup 1.0000x reference)
//
#include <hip/hip_runtime.h>

#define N_SAMPLES 32768
#define N_EMBED   10000
#define KPAD      10240        // padded cluster count
#define HLEN      5120         // clusters per half
#define ITERS     80           // HLEN / 64
#define DIM       128
#define OUT_ELEMS 4194304      // 4*8*32*32*128
#define IDX_OFF   4194304
#define LOSS_OFF  4227072

// workspace byte offsets
#define WS_CNH      0u          // f32[10240] = -||e||^2/2 (pad: -1.5e38)
#define WS_NEWSIZE  65536u      // f32[10000] (counts then new_size)
#define WS_SUMS     131072u     // f32[1280000] (sums then new_mean)
#define WS_NSAMPLE  5251072u    // f64
#define WS_LOSS     5251080u    // f64
#define WS_PACKED   5251088u    // u64[32768]
#define WS_EHI      6291456u    // f16[10240*128]  (chunk-swizzled layout)
#define WS_ELO      8912896u    // f16[10240*128]  (chunk-swizzled layout)

typedef _Float16 f16;
typedef __attribute__((ext_vector_type(8)))  _Float16 f16x8;
typedef __attribute__((ext_vector_type(16))) float    f32x16;

__device__ inline unsigned long long shflx64(unsigned long long v, int m) {
    int lo = __shfl_xor((int)(unsigned int)(v & 0xffffffffull), m, 64);
    int hi = __shfl_xor((int)(unsigned int)(v >> 32), m, 64);
    return ((unsigned long long)(unsigned int)hi << 32) | (unsigned int)lo;
}

// async global->LDS 16B copy: dst = wave-uniform LDS base + lane*16
__device__ __forceinline__ void g2l16(const void* g, void* l) {
    __builtin_amdgcn_global_load_lds(
        (const __attribute__((address_space(1))) unsigned int*)g,
        (__attribute__((address_space(3))) unsigned int*)l, 16, 0, 0);
}

// ---------------- split E (chunk-swizzled) + negated-half norms ----------------
// Storage: cluster row c = 256B; 16B chunk ch stored at position ch ^ (c & 15).
// A linear copy of a 64-row tile into LDS then yields conflict-free (uniform
// 2-way) ds_read_b128 column access.
__global__ __launch_bounds__(128) void k_prepe(const float* __restrict__ cm,
                                               f16* __restrict__ ehi,
                                               f16* __restrict__ elo,
                                               float* __restrict__ cnh) {
    __shared__ float pw[2];
    int c = blockIdx.x, d = threadIdx.x;
    float e = (c < N_EMBED) ? cm[(size_t)c * DIM + d] : 0.f;
    f16 h = (f16)e;
    int ch = d >> 3, e8 = d & 7;
    size_t pos = (size_t)c * DIM + ((ch ^ (c & 15)) << 3) + e8;
    ehi[pos] = h;
    elo[pos] = (f16)(e - (float)h);
    float s = e * e;
    #pragma unroll
    for (int off = 32; off; off >>= 1) s += __shfl_down(s, off, 64);
    if ((threadIdx.x & 63) == 0) pw[threadIdx.x >> 6] = s;
    __syncthreads();
    if (threadIdx.x == 0)
        cnh[c] = (c < N_EMBED) ? -0.5f * (pw[0] + pw[1]) : -1.5e38f;
}

// ---------------- MFMA argmin: 32x32x16, 2 tiles/iter, G2L staging ----------------
// 512 blocks = 256 sample-groups x 2 cluster-halves (half = blockIdx&1 -> even/odd
// XCD keeps one 2.6MB half L2-resident). Block: 4 waves x 32 samples; 64-cluster
// tiles (2x32) staged via global_load_lds into double-buffered LDS (64KB), shared
// by all 4 waves. Two independent acc chains (tileA/tileB) -> MFMA dep gap 64cyc.
// acc init = cnh[cluster] (per-lane scalar) -> per-reg exact running argMAX.
__global__ __launch_bounds__(256, 2) void k_argmin(const float* __restrict__ inp,
                                                   const f16* __restrict__ ehi,
                                                   const f16* __restrict__ elo,
                                                   const float* __restrict__ cnh,
                                                   unsigned long long* __restrict__ packed) {
    __shared__ __align__(16) char lds[65536];
    const int tid = threadIdx.x;
    const int wave = tid >> 6, lane = tid & 63;
    const int l31 = lane & 31, h = lane >> 5;
    const int g = blockIdx.x >> 1;
    const int kbase = (blockIdx.x & 1) * HLEN;
    const int sbase = g * 128 + wave * 32;

    // ---- A-frags: in-register f16 hi/lo split of this lane's sample row ----
    // row = l31 -> sample sbase+l31; k = ks*16 + h*8 + e
    f16x8 ah[8], al[8];
    {
        const float* xr = inp + (size_t)(sbase + l31) * DIM + h * 8;
        #pragma unroll
        for (int ks = 0; ks < 8; ++ks) {
            float4 u0 = *(const float4*)(xr + ks * 16);
            float4 u1 = *(const float4*)(xr + ks * 16 + 4);
            float v[8] = {u0.x, u0.y, u0.z, u0.w, u1.x, u1.y, u1.z, u1.w};
            f16x8 hv, lv;
            #pragma unroll
            for (int e = 0; e < 8; ++e) {
                f16 hh = (f16)v[e];
                hv[e] = hh;
                lv[e] = (f16)(v[e] - (float)hh);
            }
            ah[ks] = hv; al[ks] = lv;
        }
    }

    // ---- per-lane ds_read addrs (loop-invariant): cluster row r=l31, chunk
    // (ks<<1)|h stored at chunk ^ (r&15) -> addr = base | ((ks^km)<<5)
    int adr[8];
    {
        const int km = (l31 >> 1) & 7;
        const int base = l31 * 256 + ((h ^ (l31 & 1)) << 4);
        #pragma unroll
        for (int ks = 0; ks < 8; ++ks) adr[ks] = base | ((ks ^ km) << 5);
    }

    float best[16];
    int bi[16];
    #pragma unroll
    for (int r = 0; r < 16; ++r) { best[r] = -3.4e38f; bi[r] = 0; }

    // ---- staging: linear 32KB tile copy (16KB hi + 16KB lo), 8 G2L per wave ----
    auto STAGE = [&](int buf, int c0) {
        const char* sh = (const char*)ehi + (size_t)c0 * 256 + wave * 4096 + lane * 16;
        const char* sl = (const char*)elo + (size_t)c0 * 256 + wave * 4096 + lane * 16;
        char* dh = lds + buf * 32768 + wave * 4096;
        #pragma unroll
        for (int j = 0; j < 4; ++j) {
            g2l16(sh + j * 1024, dh + j * 1024);
            g2l16(sl + j * 1024, dh + j * 1024 + 16384);
        }
    };

    STAGE(0, kbase);
    float cnA = cnh[kbase + l31], cnB = cnh[kbase + 32 + l31];
    __syncthreads();

    int cur = 0;
    for (int it = 0; it < ITERS; ++it) {
        const int c0 = kbase + it * 64;
        const bool more = (it < ITERS - 1);
        float cnA2 = 0.f, cnB2 = 0.f;
        if (more) {
            STAGE(cur ^ 1, c0 + 64);
            cnA2 = cnh[c0 + 64 + l31];
            cnB2 = cnh[c0 + 96 + l31];
        }

        const char* lr = lds + cur * 32768;
        f32x16 aA, aB;
        #pragma unroll
        for (int r = 0; r < 16; ++r) { aA[r] = cnA; aB[r] = cnB; }
        #pragma unroll
        for (int ks = 0; ks < 8; ++ks) {
            f16x8 bhA = *(const f16x8*)(lr + adr[ks]);
            f16x8 bhB = *(const f16x8*)(lr + adr[ks] + 8192);
            f16x8 blA = *(const f16x8*)(lr + adr[ks] + 16384);
            f16x8 blB = *(const f16x8*)(lr + adr[ks] + 24576);
            aA = __builtin_amdgcn_mfma_f32_32x32x16_f16(ah[ks], bhA, aA, 0, 0, 0);
            aB = __builtin_amdgcn_mfma_f32_32x32x16_f16(ah[ks], bhB, aB, 0, 0, 0);
            aA = __builtin_amdgcn_mfma_f32_32x32x16_f16(al[ks], bhA, aA, 0, 0, 0);
            aB = __builtin_amdgcn_mfma_f32_32x32x16_f16(al[ks], bhB, aB, 0, 0, 0);
            aA = __builtin_amdgcn_mfma_f32_32x32x16_f16(ah[ks], blA, aA, 0, 0, 0);
            aB = __builtin_amdgcn_mfma_f32_32x32x16_f16(ah[ks], blB, aB, 0, 0, 0);
        }

        // exact per-reg running argMAX; ascending candidate order keeps first-min ties
        const int cvA = c0 + l31, cvB = cvA + 32;
        #pragma unroll
        for (int r = 0; r < 16; ++r) {
            bool gA = aA[r] > best[r];
            best[r] = gA ? aA[r] : best[r];
            bi[r]   = gA ? cvA : bi[r];
            bool gB = aB[r] > best[r];
            best[r] = gB ? aB[r] : best[r];
            bi[r]   = gB ? cvB : bi[r];
        }

        if (more) {
            __syncthreads();   // drains G2L (vmcnt) + publishes next buffer
            cnA = cnA2; cnB = cnB2;
            cur ^= 1;
        }
    }

    // ---- epilogue: per-reg reduce across the 32 cluster-lanes of this half ----
    // reg r holds sample row (r&3) + 8*(r>>2) + 4*h
    #pragma unroll
    for (int r = 0; r < 16; ++r) {
        unsigned int b = __float_as_uint(best[r]);
        unsigned int t = (b & 0x80000000u) ? ~b : (b | 0x80000000u); // monotone inc
        unsigned long long p = ((unsigned long long)(~t) << 32) | (unsigned int)bi[r];
        #pragma unroll
        for (int m = 1; m < 32; m <<= 1) {
            unsigned long long o = shflx64(p, m);
            p = p < o ? p : o;
        }
        if (l31 == r) {
            const int srow = (r & 3) + 8 * (r >> 2) + 4 * h;
            atomicMin(&packed[sbase + srow], p);
        }
    }
}

// ---------------- scatter: counts + sums + idx output ----------------
__global__ __launch_bounds__(256) void k_scatter(const float* __restrict__ inp,
                                                 const unsigned long long* __restrict__ packed,
                                                 float* __restrict__ sums,
                                                 float* __restrict__ counts,
                                                 float* __restrict__ idxf) {
    int j = blockIdx.x * 256 + threadIdx.x;   // < 4194304
    int i = j >> 7, d = j & 127;
    int k = (int)(unsigned int)(packed[i] & 0xFFFFFFFFull);
    atomicAdd(&sums[(size_t)k * DIM + d], inp[j]);
    if (d == 0) {
        atomicAdd(&counts[k], 1.0f);
        idxf[i] = (float)k;
    }
}

// ---------------- new_size + n_sample ----------------
__global__ __launch_bounds__(256) void k_newsize(const float* __restrict__ csize,
                                                 float* __restrict__ newsize,
                                                 double* __restrict__ nsample) {
    int k = blockIdx.x * 256 + threadIdx.x;
    float ns = 0.f;
    if (k < N_EMBED) {
        ns = csize[k] * 0.99f + newsize[k] * 0.01f;
        newsize[k] = ns;
    }
    float s = ns;
    #pragma unroll
    for (int off = 32; off; off >>= 1) s += __shfl_down(s, off, 64);
    if ((threadIdx.x & 63) == 0) atomicAdd(nsample, (double)s);
}

// ---------------- new_mean (in place over sums) ----------------
__global__ __launch_bounds__(256) void k_newmean(const float* __restrict__ csum,
                                                 float* __restrict__ sums,
                                                 const float* __restrict__ newsize,
                                                 const double* __restrict__ nsample) {
    int j = blockIdx.x * 256 + threadIdx.x;   // < 1280000
    float nsmp = (float)(*nsample);
    int k = j >> 7;
    float sm = (newsize[k] + 1e-5f) * nsmp / (nsmp + 0.1f);
    sums[j] = (csum[j] * 0.99f + sums[j] * 0.01f) / sm;
}

// ---------------- gather + output + two-stage loss ----------------
__global__ __launch_bounds__(256) void k_gather(const float* __restrict__ inp,
                                                const float* __restrict__ nm,
                                                const unsigned long long* __restrict__ packed,
                                                float* __restrict__ out,
                                                double* __restrict__ lossacc) {
    __shared__ double pw[4];
    int t0 = blockIdx.x * 256 + threadIdx.x;    // grid 512 -> t0 < 131072
    double de = 0.0;
    #pragma unroll
    for (int it = 0; it < 8; ++it) {
        int j4 = t0 + it * 131072;              // float4 index < 1048576
        int i = j4 >> 5, d4 = j4 & 31;
        int k = (int)(unsigned int)(packed[i] & 0xFFFFFFFFull);
        float4 x = ((const float4*)inp)[j4];
        float4 qv = ((const float4*)(nm + (size_t)k * DIM))[d4];
        float4 o;
        o.x = x.x + (qv.x - x.x); o.y = x.y + (qv.y - x.y);
        o.z = x.z + (qv.z - x.z); o.w = x.w + (qv.w - x.w);
        ((float4*)out)[j4] = o;
        float dx = x.x - qv.x, dy = x.y - qv.y, dz = x.z - qv.z, dw = x.w - qv.w;
        de += (double)(dx * dx + dy * dy + dz * dz + dw * dw);
    }
    #pragma unroll
    for (int off = 32; off; off >>= 1) de += __shfl_down(de, off, 64);
    if ((threadIdx.x & 63) == 0) pw[threadIdx.x >> 6] = de;
    __syncthreads();
    if (threadIdx.x == 0)
        atomicAdd(lossacc, pw[0] + pw[1] + pw[2] + pw[3]);
}

__global__ void k_lossfinal(const double* __restrict__ lossacc,
                            float* __restrict__ lossout) {
    *lossout = 0.25f * (float)(*lossacc / (double)OUT_ELEMS);
}

extern "C" void kernel_launch(void* const* d_in, const int* in_sizes, int n_in,
                              void* d_out, int out_size, void* d_ws, size_t ws_size,
                              hipStream_t stream) {
    const float* inp   = (const float*)d_in[0];
    const float* cmean = (const float*)d_in[1];
    const float* csize = (const float*)d_in[2];
    const float* csum  = (const float*)d_in[3];
    float* out = (float*)d_out;
    char*  ws  = (char*)d_ws;

    float*  cnh     = (float*)(ws + WS_CNH);
    float*  newsize = (float*)(ws + WS_NEWSIZE);
    float*  sums    = (float*)(ws + WS_SUMS);
    double* nsample = (double*)(ws + WS_NSAMPLE);
    double* lossacc = (double*)(ws + WS_LOSS);
    unsigned long long* packed = (unsigned long long*)(ws + WS_PACKED);
    f16* ehi = (f16*)(ws + WS_EHI);
    f16* elo = (f16*)(ws + WS_ELO);
    float* idxf = out + IDX_OFF;

    // zero counts/sums/nsample/loss; fill packed with 0xFF (u64 max)
    hipMemsetAsync(ws + WS_NEWSIZE, 0, (WS_LOSS + 8) - WS_NEWSIZE, stream);
    hipMemsetAsync(ws + WS_PACKED, 0xFF, (size_t)N_SAMPLES * 8, stream);

    k_prepe  <<<KPAD, 128, 0, stream>>>(cmean, ehi, elo, cnh);
    k_argmin <<<512, 256, 0, stream>>>(inp, ehi, elo, cnh, packed);
    k_scatter<<<OUT_ELEMS / 256, 256, 0, stream>>>(inp, packed, sums, newsize, idxf);
    k_newsize<<<(N_EMBED + 255) / 256, 256, 0, stream>>>(csize, newsize, nsample);
    k_newmean<<<(N_EMBED * DIM) / 256, 256, 0, stream>>>(csum, sums, newsize, nsample);
    k_gather <<<512, 256, 0, stream>>>(inp, sums, packed, out, lossacc);
    k_lossfinal<<<1, 1, 0, stream>>>(lossacc, out + LOSS_OFF);
}